// Round 5
// baseline (126.207 us; speedup 1.0000x reference)
//
#include <hip/hip_runtime.h>
#include <math.h>

#define NTOK  16384
#define HDIM  2048
#define NEXP  64
#define TOPK  6
#define TB    32           // tokens per block (4 token-groups x 8)
#define CH    64           // h per chunk per half
#define NCH   16           // chunks per half (16 * 64 = 1024)
#define HHALF 1024

// LDS: staged W (transposed) unioned with epilogue buffers.
union SMem {
    float4 wt[2][16][NEXP];      // [half][slot][expert] = w[e][hh*1024+c*64+4*slot+j], 32 KB
    struct {
        float4 cmb[4][8][NEXP];  // hh=1 partials: [tg][t][e], 32 KB
        float  lg[TB][65];       // logits, padded, 8.3 KB
    } e;
};

__device__ __forceinline__ void gload_lds16(const float* g, void* l) {
    __builtin_amdgcn_global_load_lds(
        (const __attribute__((address_space(1))) unsigned int*)g,
        (__attribute__((address_space(3))) unsigned int*)l, 16, 0, 0);
}

__global__ __launch_bounds__(512, 4) void moe_gate_kernel(
        const float* __restrict__ x,
        const float* __restrict__ w,
        float* __restrict__ out)
{
    __shared__ SMem sm;

    const int tid  = threadIdx.x;
    const int lane = tid & 63;                       // = expert owned by this lane
    const int wv   = __builtin_amdgcn_readfirstlane(tid >> 6);
    const int tg   = wv >> 1;                        // token group 0..3 (8 tokens each)
    const int hh   = wv & 1;                         // h-half 0/1
    const int tbase = blockIdx.x * TB;

    // wave-uniform x base -> scalar/uniform loads (no LDS, no per-lane VGPR traffic)
    const float* xw = x + (size_t)(tbase + tg * 8) * HDIM + hh * HHALF;

    // acc[t]: float4 of j = h%4 partials (ascending h within this half) for (token, expert=lane)
    float4 acc[8];
    #pragma unroll
    for (int t = 0; t < 8; ++t) acc[t] = make_float4(0.f, 0.f, 0.f, 0.f);

    for (int c = 0; c < NCH; ++c) {
        __syncthreads();   // previous chunk's reads complete before overwrite

        // ---- stage W chunk, transposed, direct-to-LDS ----
        // wave wv handles pairs p = 8*wv..8*wv+7: (half = p>>4, slot = p&15).
        // LDS dest base uniform; lane l lands at +16*l = wt[half][slot][l].
        // Per-lane global src = expert row l  -> transpose for free.
        #pragma unroll
        for (int k = 0; k < 8; ++k) {
            const int p  = wv * 8 + k;
            const int sh = p >> 4;
            const int sl = p & 15;
            const float* g = w + (size_t)lane * HDIM + sh * HHALF + c * CH + 4 * sl;
            gload_lds16(g, &sm.wt[sh][sl][0]);
        }
        __syncthreads();   // drains vmcnt: staged data visible

        // ---- compute: 16 steps x (1 ds_read_b128 + 8 uniform x-loads + 32 v_fma) ----
        const float* xc = xw + c * CH;
        #pragma unroll
        for (int s = 0; s < 16; ++s) {
            const float4 wv4 = sm.wt[hh][s][lane];
            #pragma unroll
            for (int t = 0; t < 8; ++t) {
                const float4 xv = *(const float4*)(xc + t * HDIM + 4 * s);
                acc[t].x = fmaf(xv.x, wv4.x, acc[t].x);
                acc[t].y = fmaf(xv.y, wv4.y, acc[t].y);
                acc[t].z = fmaf(xv.z, wv4.z, acc[t].z);
                acc[t].w = fmaf(xv.w, wv4.w, acc[t].w);
            }
        }
    }

    __syncthreads();   // all compute done before overlaying epilogue buffers

    // ---- cross-half combine: hh=1 stores verbatim; hh=0 adds lane-wise (R4's proven seam) ----
    if (hh == 1) {
        #pragma unroll
        for (int t = 0; t < 8; ++t)
            sm.e.cmb[tg][t][lane] = acc[t];
    }
    __syncthreads();
    if (hh == 0) {
        #pragma unroll
        for (int t = 0; t < 8; ++t) {
            const float4 o  = sm.e.cmb[tg][t][lane];
            const float  J0 = acc[t].x + o.x;
            const float  J1 = acc[t].y + o.y;
            const float  J2 = acc[t].z + o.z;
            const float  J3 = acc[t].w + o.w;
            sm.e.lg[tg * 8 + t][lane] = (J0 + J2) + (J1 + J3);   // np SSE combine order
        }
    }
    __syncthreads();

    // ---- per-token top-6 + softmax + renorm (identical numerics to R1-R4) ----
    if (tid < TB) {
        float val[TOPK];
        int   idx[TOPK];
        #pragma unroll
        for (int k = 0; k < TOPK; ++k) { val[k] = -3.0e38f; idx[k] = 0; }

        for (int e = 0; e < NEXP; ++e) {
            float cv = sm.e.lg[tid][e];
            int   ci = e;
            #pragma unroll
            for (int k = 0; k < TOPK; ++k) {
                if (cv > val[k]) {                 // strict >: lowest index wins ties
                    const float tv = val[k]; const int ti = idx[k];
                    val[k] = cv; idx[k] = ci;
                    cv = tv; ci = ti;
                }
            }
        }

        const float m = val[0];
        float ex[TOPK];
        float s = 0.f;
        #pragma unroll
        for (int k = 0; k < TOPK; ++k) { ex[k] = expf(val[k] - m); s += ex[k]; }
        float p[TOPK];
        float d = 0.f;
        #pragma unroll
        for (int k = 0; k < TOPK; ++k) { p[k] = ex[k] / s; d += p[k]; }
        d += 1e-20f;

        const int tg2 = tbase + tid;
        float* oi = out;                           // idx chunk   [NTOK*TOPK]
        float* ow = out + (size_t)NTOK * TOPK;     // weight chunk
        #pragma unroll
        for (int k = 0; k < TOPK; ++k) {
            oi[tg2 * TOPK + k] = (float)idx[k];
            ow[tg2 * TOPK + k] = p[k] / d;
        }
    }
}

extern "C" void kernel_launch(void* const* d_in, const int* in_sizes, int n_in,
                              void* d_out, int out_size, void* d_ws, size_t ws_size,
                              hipStream_t stream) {
    const float* x = (const float*)d_in[0];
    const float* w = (const float*)d_in[1];
    float* out = (float*)d_out;
    dim3 grid(NTOK / TB);   // 512 blocks -> 2 blocks/CU, 16 waves/CU
    dim3 block(512);        // 8 waves: (tg, hh) = (wv>>1, wv&1)
    hipLaunchKernelGGL(moe_gate_kernel, grid, block, 0, stream, x, w, out);
}